// Round 1
// baseline (406.302 us; speedup 1.0000x reference)
//
#include <hip/hip_runtime.h>
#include <cstdint>
#include <cstddef>

#define B_SZ 16384
#define X_D  64
#define U_D  16
#define Z_D  32
#define H_D  1024
#define A_D  256
#define DT_C 0.02f

typedef _Float16 f16;
typedef f16   f16x8 __attribute__((ext_vector_type(8)));
typedef f16   f16x4 __attribute__((ext_vector_type(4)));
typedef float f32x4 __attribute__((ext_vector_type(4)));

#define AS1 __attribute__((address_space(1)))
#define AS3 __attribute__((address_space(3)))

__device__ __forceinline__ void gld_lds16(const void* g, void* l) {
    __builtin_amdgcn_global_load_lds((AS1 void*)(g), (AS3 void*)(l), 16, 0, 0);
}

// ---------------------------------------------------------------------------
// Generic f16 MFMA GEMM: C[M,N] = act(A[M,K] @ Bt[N,K]^T + bias)
// A row-major [M,K] f16, Bt row-major [N,K] f16 (i.e. W^T), bias f32[N].
// 256 threads = 4 waves arranged WM x WN; wave tile (BM/WM) x (BN/WN);
// 16x16x32 f16 MFMA subtiles. K % BK == 0, M % BM == 0, N % BN == 0 assumed.
// LDS staged via global_load_lds width 16 with XOR segment swizzle.
// ---------------------------------------------------------------------------
template<int BM, int BN, int BK, int WM, int WN, bool SILU, bool OUT16>
__launch_bounds__(256)
__global__ void gemm_f16(const f16* __restrict__ A, const f16* __restrict__ Bt,
                         const float* __restrict__ bias, void* __restrict__ Cp,
                         int M, int N, int K)
{
    constexpr int SEGROW = BK / 8;                       // 16B segments per row
    constexpr int SMASK  = (SEGROW < 8 ? SEGROW : 8) - 1;
    constexpr int WTM = BM / WM, WTN = BN / WN;
    constexpr int RM = WTM / 16, RN = WTN / 16;
    constexpr int ITA = (BM * SEGROW) / 256;             // full iterations (exact)
    constexpr int ITB = (BN * SEGROW) / 256;

    __shared__ f16 As[BM * BK];
    __shared__ f16 Bs[BN * BK];

    const int tid  = threadIdx.x;
    const int lane = tid & 63;
    const int wave = tid >> 6;
    const int wm = wave / WN, wn = wave % WN;
    const int l15 = lane & 15, quad = lane >> 4;

    const size_t arow0 = (size_t)blockIdx.x * BM;
    const size_t brow0 = (size_t)blockIdx.y * BN;

    f32x4 zero = {0.f, 0.f, 0.f, 0.f};
    f32x4 acc[RM][RN];
#pragma unroll
    for (int i = 0; i < RM; ++i)
#pragma unroll
        for (int j = 0; j < RN; ++j) acc[i][j] = zero;

    for (int k0 = 0; k0 < K; k0 += BK) {
#pragma unroll
        for (int it = 0; it < ITA; ++it) {
            int s = it * 256 + tid;
            int row = s / SEGROW, st = s % SEGROW;
            int sg = st ^ (row & SMASK);
            gld_lds16(A + (arow0 + row) * K + k0 + sg * 8, &As[s * 8]);
        }
#pragma unroll
        for (int it = 0; it < ITB; ++it) {
            int s = it * 256 + tid;
            int row = s / SEGROW, st = s % SEGROW;
            int sg = st ^ (row & SMASK);
            gld_lds16(Bt + (brow0 + row) * K + k0 + sg * 8, &Bs[s * 8]);
        }
        __syncthreads();

#pragma unroll
        for (int kk = 0; kk < BK; kk += 32) {
            f16x8 af[RM], bf[RN];
#pragma unroll
            for (int i = 0; i < RM; ++i) {
                int row = wm * WTM + i * 16 + l15;
                int st  = ((kk >> 3) + quad) ^ (row & SMASK);
                af[i] = *(const f16x8*)&As[(row * SEGROW + st) * 8];
            }
#pragma unroll
            for (int j = 0; j < RN; ++j) {
                int row = wn * WTN + j * 16 + l15;
                int st  = ((kk >> 3) + quad) ^ (row & SMASK);
                bf[j] = *(const f16x8*)&Bs[(row * SEGROW + st) * 8];
            }
#pragma unroll
            for (int i = 0; i < RM; ++i)
#pragma unroll
                for (int j = 0; j < RN; ++j)
                    acc[i][j] = __builtin_amdgcn_mfma_f32_16x16x32_f16(
                        af[i], bf[j], acc[i][j], 0, 0, 0);
        }
        __syncthreads();
    }

    // Epilogue: D layout col = lane&15, row = quad*4 + r  [m89-verified]
    const int rowb = (int)arow0 + wm * WTM;
    const int colb = (int)brow0 + wn * WTN;
#pragma unroll
    for (int j = 0; j < RN; ++j) {
        int col = colb + j * 16 + l15;
        float bv = bias[col];
#pragma unroll
        for (int i = 0; i < RM; ++i) {
#pragma unroll
            for (int r = 0; r < 4; ++r) {
                int row = rowb + i * 16 + quad * 4 + r;
                float v = acc[i][j][r] + bv;
                if (SILU) v = v * (1.0f / (1.0f + __expf(-v)));
                if (OUT16) ((f16*)Cp)[(size_t)row * N + col] = (f16)v;
                else       ((float*)Cp)[(size_t)row * N + col] = v;
            }
        }
    }
}

// in: f32 [K,N] row-major  ->  out: f16 [N,K] row-major (transposed cast)
__global__ void transpose_w_f16(const float* __restrict__ in, f16* __restrict__ out,
                                int K, int N)
{
    __shared__ float t[32][33];
    int n0 = blockIdx.x << 5, k0 = blockIdx.y << 5;
    int tx = threadIdx.x, ty = threadIdx.y;      // (32, 8)
#pragma unroll
    for (int i = 0; i < 32; i += 8)
        t[ty + i][tx] = in[(size_t)(k0 + ty + i) * N + n0 + tx];
    __syncthreads();
#pragma unroll
    for (int i = 0; i < 32; i += 8)
        out[(size_t)(n0 + ty + i) * K + k0 + tx] = (f16)t[tx][ty + i];
}

// f32 -> f16, 4 elements per thread; n must be divisible by 1024
__global__ void cvt_f32_f16(const float* __restrict__ in, f16* __restrict__ out)
{
    int i = (blockIdx.x * 256 + threadIdx.x) * 4;
    float4 v = *(const float4*)(in + i);
    f16x4 o = { (f16)v.x, (f16)v.y, (f16)v.z, (f16)v.w };
    *(f16x4*)(out + i) = o;
}

// Koopman block-rotation update: one thread per (sample, z-component)
__global__ void koopman_k(const float* __restrict__ zf, const float* __restrict__ auxf,
                          const f16* __restrict__ bmat, const float* __restrict__ u,
                          f16* __restrict__ zn)
{
    int idx = blockIdx.x * 256 + threadIdx.x;    // B*32 total
    int i = idx >> 5, zi = idx & 31;
    int base = (i << 5) + ((zi >> 1) << 1);
    float a = auxf[base], b = auxf[base + 1];
    float f = __expf(a * DT_C);
    float c = __cosf(b * DT_C);
    float s = __sinf(b * DT_C);
    float z0 = zf[base], z1 = zf[base + 1];
    float Az = (zi & 1) ? f * (s * z0 + c * z1) : f * (c * z0 - s * z1);
    const f16*   br = bmat + ((size_t)idx << 4);
    const float* ur = u + ((size_t)i << 4);
    float Bu = 0.f;
#pragma unroll
    for (int k = 0; k < 16; ++k) Bu += (float)br[k] * ur[k];
    zn[idx] = (f16)(zf[idx] + DT_C * (Az + Bu));
}

extern "C" void kernel_launch(void* const* d_in, const int* in_sizes, int n_in,
                              void* d_out, int out_size, void* d_ws, size_t ws_size,
                              hipStream_t stream)
{
    (void)in_sizes; (void)n_in; (void)out_size; (void)ws_size;
    const float* x    = (const float*)d_in[0];
    const float* u    = (const float*)d_in[1];
    const float* e_w1 = (const float*)d_in[2];  const float* e_b1 = (const float*)d_in[3];
    const float* e_w2 = (const float*)d_in[4];  const float* e_b2 = (const float*)d_in[5];
    const float* e_w3 = (const float*)d_in[6];  const float* e_b3 = (const float*)d_in[7];
    const float* d_w1 = (const float*)d_in[8];  const float* d_b1 = (const float*)d_in[9];
    const float* d_w2 = (const float*)d_in[10]; const float* d_b2 = (const float*)d_in[11];
    const float* d_w3 = (const float*)d_in[12]; const float* d_b3 = (const float*)d_in[13];
    const float* d_w4 = (const float*)d_in[14]; const float* d_b4 = (const float*)d_in[15];
    const float* a_w1 = (const float*)d_in[16]; const float* a_b1 = (const float*)d_in[17];
    const float* a_w2 = (const float*)d_in[18]; const float* a_b2 = (const float*)d_in[19];
    const float* a_w3 = (const float*)d_in[20]; const float* a_b3 = (const float*)d_in[21];
    const float* b_w1 = (const float*)d_in[22]; const float* b_b1 = (const float*)d_in[23];
    const float* b_w2 = (const float*)d_in[24]; const float* b_b2 = (const float*)d_in[25];
    const float* b_w3 = (const float*)d_in[26]; const float* b_b3 = (const float*)d_in[27];

    char* p = (char*)d_ws;
    auto alloc = [&](size_t nbytes) -> void* {
        void* r = (void*)p;
        p += (nbytes + 255) & ~(size_t)255;
        return r;
    };
    // activations
    f16*   xb   = (f16*)  alloc((size_t)B_SZ * X_D * 2);
    f16*   h1   = (f16*)  alloc((size_t)B_SZ * H_D * 2);
    f16*   h2   = (f16*)  alloc((size_t)B_SZ * H_D * 2);
    float* zf   = (float*)alloc((size_t)B_SZ * Z_D * 4);
    float* auxf = (float*)alloc((size_t)B_SZ * Z_D * 4);
    f16*   p1   = (f16*)  alloc((size_t)B_SZ * A_D * 2);
    f16*   p2   = (f16*)  alloc((size_t)B_SZ * A_D * 2);
    f16*   bmat = (f16*)  alloc((size_t)B_SZ * (Z_D * U_D) * 2);
    f16*   znb  = (f16*)  alloc((size_t)B_SZ * Z_D * 2);
    // transposed f16 weights [N][K]
    f16* e_w1t = (f16*)alloc((size_t)H_D * X_D * 2);
    f16* e_w2t = (f16*)alloc((size_t)H_D * H_D * 2);
    f16* e_w3t = (f16*)alloc((size_t)Z_D * H_D * 2);
    f16* d_w1t = (f16*)alloc((size_t)H_D * Z_D * 2);
    f16* d_w2t = (f16*)alloc((size_t)H_D * H_D * 2);
    f16* d_w3t = (f16*)alloc((size_t)H_D * H_D * 2);
    f16* d_w4t = (f16*)alloc((size_t)X_D * H_D * 2);
    f16* a_w1t = (f16*)alloc((size_t)A_D * X_D * 2);
    f16* a_w2t = (f16*)alloc((size_t)A_D * A_D * 2);
    f16* a_w3t = (f16*)alloc((size_t)Z_D * A_D * 2);
    f16* b_w1t = (f16*)alloc((size_t)A_D * X_D * 2);
    f16* b_w2t = (f16*)alloc((size_t)A_D * A_D * 2);
    f16* b_w3t = (f16*)alloc((size_t)(Z_D * U_D) * A_D * 2);

    dim3 tb(32, 8);
    auto T = [&](const float* w, f16* wt, int K, int N) {
        transpose_w_f16<<<dim3(N / 32, K / 32), tb, 0, stream>>>(w, wt, K, N);
    };
    T(e_w1, e_w1t, X_D, H_D);
    T(e_w2, e_w2t, H_D, H_D);
    T(e_w3, e_w3t, H_D, Z_D);
    T(d_w1, d_w1t, Z_D, H_D);
    T(d_w2, d_w2t, H_D, H_D);
    T(d_w3, d_w3t, H_D, H_D);
    T(d_w4, d_w4t, H_D, X_D);
    T(a_w1, a_w1t, X_D, A_D);
    T(a_w2, a_w2t, A_D, A_D);
    T(a_w3, a_w3t, A_D, Z_D);
    T(b_w1, b_w1t, X_D, A_D);
    T(b_w2, b_w2t, A_D, A_D);
    T(b_w3, b_w3t, A_D, Z_D * U_D);

    cvt_f32_f16<<<(B_SZ * X_D) / 1024, 256, 0, stream>>>(x, xb);

    // ---- encoder ----
    gemm_f16<128,128,64,2,2,true, true ><<<dim3(B_SZ/128, H_D/128), 256, 0, stream>>>(
        xb, e_w1t, e_b1, h1, B_SZ, H_D, X_D);
    gemm_f16<128,128,64,2,2,true, true ><<<dim3(B_SZ/128, H_D/128), 256, 0, stream>>>(
        h1, e_w2t, e_b2, h2, B_SZ, H_D, H_D);
    gemm_f16<64,32,64,4,1,false,false><<<dim3(B_SZ/64, 1), 256, 0, stream>>>(
        h2, e_w3t, e_b3, zf, B_SZ, Z_D, H_D);
    // ---- aux MLP ----
    gemm_f16<128,128,64,2,2,true, true ><<<dim3(B_SZ/128, A_D/128), 256, 0, stream>>>(
        xb, a_w1t, a_b1, p1, B_SZ, A_D, X_D);
    gemm_f16<128,128,64,2,2,true, true ><<<dim3(B_SZ/128, A_D/128), 256, 0, stream>>>(
        p1, a_w2t, a_b2, p2, B_SZ, A_D, A_D);
    gemm_f16<64,32,64,4,1,false,false><<<dim3(B_SZ/64, 1), 256, 0, stream>>>(
        p2, a_w3t, a_b3, auxf, B_SZ, Z_D, A_D);
    // ---- B-matrix MLP ----
    gemm_f16<128,128,64,2,2,true, true ><<<dim3(B_SZ/128, A_D/128), 256, 0, stream>>>(
        xb, b_w1t, b_b1, p1, B_SZ, A_D, X_D);
    gemm_f16<128,128,64,2,2,true, true ><<<dim3(B_SZ/128, A_D/128), 256, 0, stream>>>(
        p1, b_w2t, b_b2, p2, B_SZ, A_D, A_D);
    gemm_f16<128,128,64,2,2,false,true ><<<dim3(B_SZ/128, (Z_D*U_D)/128), 256, 0, stream>>>(
        p2, b_w3t, b_b3, bmat, B_SZ, Z_D * U_D, A_D);
    // ---- Koopman update ----
    koopman_k<<<(B_SZ * Z_D) / 256, 256, 0, stream>>>(zf, auxf, bmat, u, znb);
    // ---- decoder ----
    gemm_f16<128,128,32,2,2,true, true ><<<dim3(B_SZ/128, H_D/128), 256, 0, stream>>>(
        znb, d_w1t, d_b1, h1, B_SZ, H_D, Z_D);
    gemm_f16<128,128,64,2,2,true, true ><<<dim3(B_SZ/128, H_D/128), 256, 0, stream>>>(
        h1, d_w2t, d_b2, h2, B_SZ, H_D, H_D);
    gemm_f16<128,128,64,2,2,true, true ><<<dim3(B_SZ/128, H_D/128), 256, 0, stream>>>(
        h2, d_w3t, d_b3, h1, B_SZ, H_D, H_D);
    gemm_f16<64,64,64,2,2,false,false><<<dim3(B_SZ/64, 1), 256, 0, stream>>>(
        h1, d_w4t, d_b4, (float*)d_out, B_SZ, X_D, H_D);
}

// Round 2
// 378.631 us; speedup vs baseline: 1.0731x; 1.0731x over previous
//
#include <hip/hip_runtime.h>
#include <cstdint>
#include <cstddef>

#define B_SZ 16384
#define X_D  64
#define U_D  16
#define Z_D  32
#define H_D  1024
#define A_D  256
#define DT_C 0.02f

typedef _Float16 f16;
typedef f16   f16x8 __attribute__((ext_vector_type(8)));
typedef f16   f16x4 __attribute__((ext_vector_type(4)));
typedef float f32x4 __attribute__((ext_vector_type(4)));

#define AS1 __attribute__((address_space(1)))
#define AS3 __attribute__((address_space(3)))

__device__ __forceinline__ void gld_lds16(const void* g, void* l) {
    __builtin_amdgcn_global_load_lds((AS1 void*)(g), (AS3 void*)(l), 16, 0, 0);
}

struct GArg {
    const f16*  A;     // [M, lda] activations (row-major subview)
    const f16*  W;     // [N, K]   transposed weights, ld == K
    const float* bias; // [N]
    void*       C;     // output
    const float* U;    // u input (OM==2 only)
    int lda, ldc, K;
};
struct GPair { GArg g[2]; };

// ---------------------------------------------------------------------------
// f16 MFMA GEMM: C = act(A @ W^T + bias). 4 waves, wave tile (BM/WM)x(BN/WN),
// 16x16x32 MFMA, global_load_lds(16B) staging with XOR segment swizzle.
// OM: 0 = scalar f32 store; 1 = f16 via LDS repack + dwordx4 (BN must be 128);
//     2 = Bu epilogue: contract cols-of-16 against U, write f32 [M,32].
// blockIdx.z selects p.g[z] (launch pairs of same-shape GEMMs together).
// ---------------------------------------------------------------------------
template<int BM,int BN,int BK,int WM,int WN,bool SILU,int OM>
__launch_bounds__(256)
__global__ void gemm_k(GPair p)
{
    static_assert(OM != 1 || BN == 128, "OM1 repack assumes BN=128");
    const GArg ga = p.g[blockIdx.z];

    constexpr int SEGROW = BK / 8;
    constexpr int SMASK  = (SEGROW < 8 ? SEGROW : 8) - 1;
    constexpr int WTM = BM / WM, WTN = BN / WN;
    constexpr int RM = WTM / 16, RN = WTN / 16;
    constexpr int ITA = (BM * SEGROW) / 256;
    constexpr int ITB = (BN * SEGROW) / 256;

    constexpr int STAGE_B = (BM + BN) * BK * 2;
    constexpr int CS_B    = (OM == 1) ? BM * BN * 2 : 0;
    constexpr int SMEM_B  = STAGE_B > CS_B ? STAGE_B : CS_B;
    __shared__ __align__(16) char smem[SMEM_B];
    f16* As = (f16*)smem;
    f16* Bs = As + BM * BK;

    const int tid  = threadIdx.x;
    const int lane = tid & 63;
    const int wave = tid >> 6;
    const int wm = wave / WN, wn = wave % WN;
    const int l15 = lane & 15, quad = lane >> 4;

    const size_t arow0 = (size_t)blockIdx.x * BM;
    const size_t brow0 = (size_t)blockIdx.y * BN;
    const int lda = ga.lda, K = ga.K;

    f32x4 zero = {0.f, 0.f, 0.f, 0.f};
    f32x4 acc[RM][RN];
#pragma unroll
    for (int i = 0; i < RM; ++i)
#pragma unroll
        for (int j = 0; j < RN; ++j) acc[i][j] = zero;

    for (int k0 = 0; k0 < K; k0 += BK) {
#pragma unroll
        for (int it = 0; it < ITA; ++it) {
            int s = it * 256 + tid;
            int row = s / SEGROW, st = s % SEGROW;
            int sg = st ^ (row & SMASK);
            gld_lds16(ga.A + (arow0 + row) * lda + k0 + sg * 8, &As[s * 8]);
        }
#pragma unroll
        for (int it = 0; it < ITB; ++it) {
            int s = it * 256 + tid;
            int row = s / SEGROW, st = s % SEGROW;
            int sg = st ^ (row & SMASK);
            gld_lds16(ga.W + (brow0 + row) * K + k0 + sg * 8, &Bs[s * 8]);
        }
        __syncthreads();

#pragma unroll
        for (int kk = 0; kk < BK; kk += 32) {
            f16x8 af[RM], bf[RN];
#pragma unroll
            for (int i = 0; i < RM; ++i) {
                int row = wm * WTM + i * 16 + l15;
                int st  = ((kk >> 3) + quad) ^ (row & SMASK);
                af[i] = *(const f16x8*)&As[(row * SEGROW + st) * 8];
            }
#pragma unroll
            for (int j = 0; j < RN; ++j) {
                int row = wn * WTN + j * 16 + l15;
                int st  = ((kk >> 3) + quad) ^ (row & SMASK);
                bf[j] = *(const f16x8*)&Bs[(row * SEGROW + st) * 8];
            }
#pragma unroll
            for (int i = 0; i < RM; ++i)
#pragma unroll
                for (int j = 0; j < RN; ++j)
                    acc[i][j] = __builtin_amdgcn_mfma_f32_16x16x32_f16(
                        af[i], bf[j], acc[i][j], 0, 0, 0);
        }
        __syncthreads();
    }

    const int rowbL = wm * WTM;
    const int colbL = wn * WTN;

    if constexpr (OM == 2) {
        // Bu[b, z] = sum_u (acc + bias)[b, z*16+u] * U[b, u]; u == l15 here.
        const int zcol0 = ((int)brow0 + colbL) >> 4;
#pragma unroll
        for (int i = 0; i < RM; ++i) {
#pragma unroll
            for (int r = 0; r < 4; ++r) {
                int row = (int)arow0 + rowbL + i * 16 + quad * 4 + r;
                float uv = ga.U[row * 16 + l15];
#pragma unroll
                for (int j = 0; j < RN; ++j) {
                    int col = (int)brow0 + colbL + j * 16 + l15;
                    float v = (acc[i][j][r] + ga.bias[col]) * uv;
                    v += __shfl_xor(v, 8, 16);
                    v += __shfl_xor(v, 4, 16);
                    v += __shfl_xor(v, 2, 16);
                    v += __shfl_xor(v, 1, 16);
                    if (l15 == 0) ((float*)ga.C)[row * 32 + zcol0 + j] = v;
                }
            }
        }
    } else if constexpr (OM == 1) {
        f16* Cs = (f16*)smem;   // safe: loop-trailing barrier already passed
#pragma unroll
        for (int j = 0; j < RN; ++j) {
            int colL = colbL + j * 16 + l15;
            float bv = ga.bias[(int)brow0 + colL];
            int chL = colL >> 3, wi = colL & 7;
#pragma unroll
            for (int i = 0; i < RM; ++i) {
#pragma unroll
                for (int r = 0; r < 4; ++r) {
                    int rowL = rowbL + i * 16 + quad * 4 + r;
                    float v = acc[i][j][r] + bv;
                    if (SILU) v = v / (1.0f + __expf(-v));
                    Cs[rowL * BN + ((chL ^ (rowL & 15)) << 3) + wi] = (f16)v;
                }
            }
        }
        __syncthreads();
        f16* Cout = (f16*)ga.C;
#pragma unroll
        for (int pass = 0; pass < (BM * BN / 8) / 256; ++pass) {
            int s = pass * 256 + tid;
            int rowL = s >> 4;          // BN/8 == 16 chunks per row
            int ch = s & 15;
            f16x8 v = *(const f16x8*)&Cs[rowL * BN + ((ch ^ (rowL & 15)) << 3)];
            *(f16x8*)&Cout[(size_t)(arow0 + rowL) * ga.ldc + brow0 + ch * 8] = v;
        }
    } else {
        float* Cout = (float*)ga.C;
#pragma unroll
        for (int j = 0; j < RN; ++j) {
            int col = (int)brow0 + colbL + j * 16 + l15;
            float bv = ga.bias[col];
#pragma unroll
            for (int i = 0; i < RM; ++i) {
#pragma unroll
                for (int r = 0; r < 4; ++r) {
                    int row = (int)arow0 + rowbL + i * 16 + quad * 4 + r;
                    float v = acc[i][j][r] + bv;
                    if (SILU) v = v / (1.0f + __expf(-v));
                    Cout[(size_t)row * ga.ldc + col] = v;
                }
            }
        }
    }
}

// ---------------------------------------------------------------------------
// One-shot prep: 13 weight transposes (f32 [K,N] -> f16 [N,K]) in 32x32 tiles,
// x f32->f16 conversion, and L1 bias concat. One launch replaces 14.
// ---------------------------------------------------------------------------
struct PrepArgs {
    const float* w[13];
    f16*         wt[13];
    int          K[13];
    int          N[13];
    const float* bsrc[3];
    float*       bias1;
    const float* x;
    f16*         xb;
};

__launch_bounds__(256)
__global__ void prep_k(PrepArgs pa, int ntrans, int ncvt)
{
    int bid = blockIdx.x;
    if (bid < ntrans) {
        int i = 0, t;
        for (;; ++i) {
            t = (pa.K[i] >> 5) * (pa.N[i] >> 5);
            if (bid < t) break;
            bid -= t;
        }
        const int K = pa.K[i], N = pa.N[i];
        const int tn = N >> 5;
        const int k0 = (bid / tn) << 5, n0 = (bid % tn) << 5;
        __shared__ float tbuf[32][33];
        const int tx = threadIdx.x & 31, ty = threadIdx.x >> 5;
        const float* src = pa.w[i];
        f16* dst = pa.wt[i];
#pragma unroll
        for (int r = 0; r < 32; r += 8)
            tbuf[ty + r][tx] = src[(size_t)(k0 + ty + r) * N + n0 + tx];
        __syncthreads();
#pragma unroll
        for (int r = 0; r < 32; r += 8)
            dst[(size_t)(n0 + ty + r) * K + k0 + tx] = (f16)tbuf[tx][ty + r];
    } else if (bid < ntrans + ncvt) {
        int i = ((bid - ntrans) * 256 + threadIdx.x) * 4;
        float4 v = *(const float4*)(pa.x + i);
        f16x4 o = {(f16)v.x, (f16)v.y, (f16)v.z, (f16)v.w};
        *(f16x4*)(pa.xb + i) = o;
    } else {
        int idx = (bid - ntrans - ncvt) * 256 + (int)threadIdx.x; // 0..1535
        float v = (idx < 1024) ? pa.bsrc[0][idx]
                : (idx < 1280) ? pa.bsrc[1][idx - 1024]
                               : pa.bsrc[2][idx - 1280];
        pa.bias1[idx] = v;
    }
}

// Koopman block-rotation update (Bu precomputed by OM2 GEMM epilogue)
__global__ void koopman_k(const float* __restrict__ zf, const float* __restrict__ auxf,
                          const float* __restrict__ Buf, f16* __restrict__ zn)
{
    int idx = blockIdx.x * 256 + threadIdx.x;    // B*32
    int zi = idx & 31;
    int base = idx & ~1;
    float a = auxf[base], b = auxf[base + 1];
    float f = __expf(a * DT_C);
    float c = __cosf(b * DT_C);
    float s = __sinf(b * DT_C);
    float z0 = zf[base], z1 = zf[base + 1];
    float Az = (zi & 1) ? f * (s * z0 + c * z1) : f * (c * z0 - s * z1);
    zn[idx] = (f16)(zf[idx] + DT_C * (Az + Buf[idx]));
}

extern "C" void kernel_launch(void* const* d_in, const int* in_sizes, int n_in,
                              void* d_out, int out_size, void* d_ws, size_t ws_size,
                              hipStream_t stream)
{
    (void)in_sizes; (void)n_in; (void)out_size; (void)ws_size;
    const float* x    = (const float*)d_in[0];
    const float* u    = (const float*)d_in[1];
    const float* e_w1 = (const float*)d_in[2];  const float* e_b1 = (const float*)d_in[3];
    const float* e_w2 = (const float*)d_in[4];  const float* e_b2 = (const float*)d_in[5];
    const float* e_w3 = (const float*)d_in[6];  const float* e_b3 = (const float*)d_in[7];
    const float* d_w1 = (const float*)d_in[8];  const float* d_b1 = (const float*)d_in[9];
    const float* d_w2 = (const float*)d_in[10]; const float* d_b2 = (const float*)d_in[11];
    const float* d_w3 = (const float*)d_in[12]; const float* d_b3 = (const float*)d_in[13];
    const float* d_w4 = (const float*)d_in[14]; const float* d_b4 = (const float*)d_in[15];
    const float* a_w1 = (const float*)d_in[16]; const float* a_b1 = (const float*)d_in[17];
    const float* a_w2 = (const float*)d_in[18]; const float* a_b2 = (const float*)d_in[19];
    const float* a_w3 = (const float*)d_in[20]; const float* a_b3 = (const float*)d_in[21];
    const float* b_w1 = (const float*)d_in[22]; const float* b_b1 = (const float*)d_in[23];
    const float* b_w2 = (const float*)d_in[24]; const float* b_b2 = (const float*)d_in[25];
    const float* b_w3 = (const float*)d_in[26]; const float* b_b3 = (const float*)d_in[27];

    char* p = (char*)d_ws;
    auto alloc = [&](size_t nbytes) -> void* {
        void* r = (void*)p;
        p += (nbytes + 255) & ~(size_t)255;
        return r;
    };
    // activations
    f16*   xb   = (f16*)  alloc((size_t)B_SZ * X_D * 2);
    f16*   cc1  = (f16*)  alloc((size_t)B_SZ * 1536 * 2);  // h1e | p1a | p1b
    f16*   cc2  = (f16*)  alloc((size_t)B_SZ * 1536 * 2);  // h2e | p2a | p2b
    float* zf   = (float*)alloc((size_t)B_SZ * Z_D * 4);
    float* auxf = (float*)alloc((size_t)B_SZ * Z_D * 4);
    float* Buf  = (float*)alloc((size_t)B_SZ * Z_D * 4);
    f16*   znb  = (f16*)  alloc((size_t)B_SZ * Z_D * 2);
    // decoder ping-pong aliases (L1/L2 buffers are dead by then)
    f16*   h1d  = cc1;   // [B,1024]
    f16*   h2d  = cc2;   // [B,1024]
    f16*   h3d  = cc1;   // [B,1024]
    // transposed f16 weights [N][K]
    f16*   W1t   = (f16*)alloc((size_t)1536 * X_D * 2);    // e|a|b layer-1 stacked
    float* bias1 = (float*)alloc(1536 * 4);
    f16* e_w2t = (f16*)alloc((size_t)H_D * H_D * 2);
    f16* e_w3t = (f16*)alloc((size_t)Z_D * H_D * 2);
    f16* d_w1t = (f16*)alloc((size_t)H_D * Z_D * 2);
    f16* d_w2t = (f16*)alloc((size_t)H_D * H_D * 2);
    f16* d_w3t = (f16*)alloc((size_t)H_D * H_D * 2);
    f16* d_w4t = (f16*)alloc((size_t)X_D * H_D * 2);
    f16* a_w2t = (f16*)alloc((size_t)A_D * A_D * 2);
    f16* a_w3t = (f16*)alloc((size_t)Z_D * A_D * 2);
    f16* b_w2t = (f16*)alloc((size_t)A_D * A_D * 2);
    f16* b_w3t = (f16*)alloc((size_t)(Z_D * U_D) * A_D * 2);

    // ---- prep: all transposes + x cvt + bias concat, one launch ----
    PrepArgs pa;
    const float* ws_[13] = {e_w1, e_w2, e_w3, d_w1, d_w2, d_w3, d_w4,
                            a_w1, a_w2, a_w3, b_w1, b_w2, b_w3};
    f16* wts_[13] = {W1t, e_w2t, e_w3t, d_w1t, d_w2t, d_w3t, d_w4t,
                     W1t + (size_t)1024 * X_D, a_w2t, a_w3t,
                     W1t + (size_t)1280 * X_D, b_w2t, b_w3t};
    int Ks_[13] = {X_D, H_D, H_D, Z_D, H_D, H_D, H_D, X_D, A_D, A_D, X_D, A_D, A_D};
    int Ns_[13] = {H_D, H_D, Z_D, H_D, H_D, H_D, X_D, A_D, A_D, Z_D, A_D, A_D, Z_D*U_D};
    int ntrans = 0;
    for (int i = 0; i < 13; ++i) {
        pa.w[i] = ws_[i]; pa.wt[i] = wts_[i]; pa.K[i] = Ks_[i]; pa.N[i] = Ns_[i];
        ntrans += (Ks_[i] >> 5) * (Ns_[i] >> 5);
    }
    pa.bsrc[0] = e_b1; pa.bsrc[1] = a_b1; pa.bsrc[2] = b_b1;
    pa.bias1 = bias1; pa.x = x; pa.xb = xb;
    const int ncvt = (B_SZ * X_D) / 1024;   // 1024 blocks
    prep_k<<<ntrans + ncvt + 6, 256, 0, stream>>>(pa, ntrans, ncvt);

    auto G = [](const f16* A, const f16* W, const float* bias, void* C,
                int lda, int ldc, int K, const float* U = nullptr) {
        GArg g; g.A = A; g.W = W; g.bias = bias; g.C = C; g.U = U;
        g.lda = lda; g.ldc = ldc; g.K = K; return g;
    };
    GPair pr;

    // ---- fused layer-1: [B,64] @ [64,1536] -> cc1 ----
    pr.g[0] = pr.g[1] = G(xb, W1t, bias1, cc1, X_D, 1536, X_D);
    gemm_k<128,128,64,2,2,true,1><<<dim3(B_SZ/128, 1536/128, 1), 256, 0, stream>>>(pr);

    // ---- encoder layer-2: cc1[:, :1024] -> cc2[:, :1024] ----
    pr.g[0] = pr.g[1] = G(cc1, e_w2t, e_b2, cc2, 1536, 1536, H_D);
    gemm_k<128,128,64,2,2,true,1><<<dim3(B_SZ/128, H_D/128, 1), 256, 0, stream>>>(pr);

    // ---- aux/bnet layer-2 (paired): cc1 subviews -> cc2 subviews ----
    pr.g[0] = G(cc1 + 1024, a_w2t, a_b2, cc2 + 1024, 1536, 1536, A_D);
    pr.g[1] = G(cc1 + 1280, b_w2t, b_b2, cc2 + 1280, 1536, 1536, A_D);
    gemm_k<128,128,64,2,2,true,1><<<dim3(B_SZ/128, A_D/128, 2), 256, 0, stream>>>(pr);

    // ---- encoder/aux layer-3 (paired): -> zf, auxf (f32 [B,32]) ----
    pr.g[0] = G(cc2,        e_w3t, e_b3, zf,   1536, Z_D, H_D);
    pr.g[1] = G(cc2 + 1024, a_w3t, a_b3, auxf, 1536, Z_D, A_D);
    gemm_k<64,32,64,4,1,false,0><<<dim3(B_SZ/64, 1, 2), 256, 0, stream>>>(pr);

    // ---- bnet layer-3 with fused Bu contraction -> Buf (f32 [B,32]) ----
    pr.g[0] = pr.g[1] = G(cc2 + 1280, b_w3t, b_b3, Buf, 1536, Z_D, A_D, u);
    gemm_k<128,128,64,2,2,false,2><<<dim3(B_SZ/128, (Z_D*U_D)/128, 1), 256, 0, stream>>>(pr);

    // ---- Koopman update -> znb (f16 [B,32]) ----
    koopman_k<<<(B_SZ * Z_D) / 256, 256, 0, stream>>>(zf, auxf, Buf, znb);

    // ---- decoder ----
    pr.g[0] = pr.g[1] = G(znb, d_w1t, d_b1, h1d, Z_D, H_D, Z_D);
    gemm_k<128,128,32,2,2,true,1><<<dim3(B_SZ/128, H_D/128, 1), 256, 0, stream>>>(pr);

    pr.g[0] = pr.g[1] = G(h1d, d_w2t, d_b2, h2d, H_D, H_D, H_D);
    gemm_k<128,128,64,2,2,true,1><<<dim3(B_SZ/128, H_D/128, 1), 256, 0, stream>>>(pr);

    pr.g[0] = pr.g[1] = G(h2d, d_w3t, d_b3, h3d, H_D, H_D, H_D);
    gemm_k<128,128,64,2,2,true,1><<<dim3(B_SZ/128, H_D/128, 1), 256, 0, stream>>>(pr);

    pr.g[0] = pr.g[1] = G(h3d, d_w4t, d_b4, d_out, H_D, X_D, H_D);
    gemm_k<64,64,64,2,2,false,0><<<dim3(B_SZ/64, 1, 1), 256, 0, stream>>>(pr);
}